// Round 6
// baseline (515.654 us; speedup 1.0000x reference)
//
#include <hip/hip_runtime.h>

// GCN via CSR pull-aggregation, float4-vectorized.
// CSR build via bucket radix partition (64 nodes/bucket): all global writes
// dense, atomics only on padded bucket counters (~320/counter) and LDS.
// packed edge = (src<<6)|(dst&63)  -- src < 2^19+..., fits 25 bits.

constexpr int H = 32;
constexpr int POOL_CHUNK = 1024;
constexpr int SHIFT = 6;              // 64 nodes per bucket
constexpr int BNODES = 1 << SHIFT;
constexpr int PAD = 16;               // ints per bucket counter slot (64B line)

// ---- CSR build ----
__global__ void bucket_hist_kernel(const int* __restrict__ dst, int* __restrict__ bcnt, int E) {
    int e = blockIdx.x * blockDim.x + threadIdx.x;
    if (e < E) {
        int d = __builtin_nontemporal_load(&dst[e]);
        atomicAdd(&bcnt[(d >> SHIFT) * PAD], 1);
    }
}

// single block, 1024 threads x 8 elems: exclusive scan of bucket counts (NB <= 8192)
__global__ void bucket_scan_kernel(const int* __restrict__ bcnt, int* __restrict__ boff,
                                   int* __restrict__ bcur, int NB) {
    __shared__ int sh[1024];
    int t = threadIdx.x;
    int base = t * 8;
    int v[8]; int s = 0;
#pragma unroll
    for (int q = 0; q < 8; q++) { int idx = base + q; v[q] = (idx < NB) ? bcnt[idx * PAD] : 0; s += v[q]; }
    sh[t] = s;
    __syncthreads();
    for (int off = 1; off < 1024; off <<= 1) {
        int u = (t >= off) ? sh[t - off] : 0;
        __syncthreads();
        sh[t] += u;
        __syncthreads();
    }
    int excl = sh[t] - s;
#pragma unroll
    for (int q = 0; q < 8; q++) {
        int idx = base + q;
        if (idx < NB) { boff[idx] = excl; bcur[idx * PAD] = excl; }
        excl += v[q];
    }
    if (t == 1023) boff[NB] = sh[1023];
}

__global__ void partition_kernel(const int* __restrict__ src, const int* __restrict__ dst,
                                 int* __restrict__ bcur, unsigned* __restrict__ packed, int E) {
    int e = blockIdx.x * blockDim.x + threadIdx.x;
    if (e >= E) return;
    int d = __builtin_nontemporal_load(&dst[e]);
    int u = __builtin_nontemporal_load(&src[e]);
    int pos = atomicAdd(&bcur[(d >> SHIFT) * PAD], 1);
    packed[pos] = ((unsigned)u << SHIFT) | (unsigned)(d & (BNODES - 1));
}

// per-bucket node counts -> dense write into cnt (consumed by scan1 in place)
__global__ void node_cnt_kernel(const unsigned* __restrict__ packed, const int* __restrict__ boff,
                                int* __restrict__ cnt, int N) {
    __shared__ int c[BNODES];
    int b = blockIdx.x;
    if (threadIdx.x < BNODES) c[threadIdx.x] = 0;
    __syncthreads();
    int s = boff[b], e2 = boff[b + 1];
    for (int k = s + threadIdx.x; k < e2; k += blockDim.x)
        atomicAdd(&c[packed[k] & (BNODES - 1)], 1);
    __syncthreads();
    int i = (b << SHIFT) + threadIdx.x;
    if (threadIdx.x < BNODES && i < N) cnt[i] = c[threadIdx.x];
}

// scan1: in-place exclusive scan of 1024-element chunks; block totals -> bsum.
// Also emits dinv[i] = rsqrt(count_i + 1) while counts are in registers.
__global__ void scan1_kernel(int* __restrict__ R, int* __restrict__ bsum,
                             float* __restrict__ dinv, int N) {
    __shared__ int sh[256];
    int base = blockIdx.x * 1024 + threadIdx.x * 4;
    int v[4]; int s = 0;
#pragma unroll
    for (int q = 0; q < 4; q++) {
        int idx = base + q;
        v[q] = (idx < N) ? R[idx] : 0;
        if (idx < N) dinv[idx] = rsqrtf((float)v[q] + 1.0f);
        s += v[q];
    }
    sh[threadIdx.x] = s;
    __syncthreads();
    for (int off = 1; off < 256; off <<= 1) {
        int t = (threadIdx.x >= off) ? sh[threadIdx.x - off] : 0;
        __syncthreads();
        sh[threadIdx.x] += t;
        __syncthreads();
    }
    int excl = sh[threadIdx.x] - s;
#pragma unroll
    for (int q = 0; q < 4; q++) { int idx = base + q; if (idx < N) R[idx] = excl; excl += v[q]; }
    if (threadIdx.x == 255) bsum[blockIdx.x] = sh[255];
}

__global__ void scan2_kernel(int* __restrict__ bsum, int nb) {
    __shared__ int sh[1024];
    int t = threadIdx.x;
    int orig = (t < nb) ? bsum[t] : 0;
    sh[t] = orig;
    __syncthreads();
    for (int off = 1; off < 1024; off <<= 1) {
        int v = (t >= off) ? sh[t - off] : 0;
        __syncthreads();
        sh[t] += v;
        __syncthreads();
    }
    if (t < nb) bsum[t] = sh[t] - orig;
}

__global__ void scan3_kernel(int* __restrict__ R, const int* __restrict__ bsum, int N) {
    int i = blockIdx.x * blockDim.x + threadIdx.x;
    if (i < N) R[i] += bsum[i >> 10];
}

// per-bucket scatter into adj: LDS cursors seeded from R; adj region contiguous
__global__ void bucket_scatter_kernel(const unsigned* __restrict__ packed, const int* __restrict__ boff,
                                      const int* __restrict__ R, int* __restrict__ adj, int N) {
    __shared__ int curs[BNODES];
    int b = blockIdx.x;
    int base = b << SHIFT;
    if (threadIdx.x < BNODES) {
        int i = base + threadIdx.x;
        curs[threadIdx.x] = (i < N) ? R[i] : 0;
    }
    __syncthreads();
    int s = boff[b], e2 = boff[b + 1];
    for (int k = s + threadIdx.x; k < e2; k += blockDim.x) {
        unsigned p = packed[k];
        int pos = atomicAdd(&curs[p & (BNODES - 1)], 1);
        adj[pos] = (int)(p >> SHIFT);
    }
}

// ---- lin1: S[i][4q..4q+3] = dinv[i] * x[i] @ W1[:,4q..4q+3]
__global__ void lin1_kernel(const float* __restrict__ x, const float4* __restrict__ W1v,
                            const float* __restrict__ dinv, float4* __restrict__ S, int N) {
    int t = blockIdx.x * blockDim.x + threadIdx.x;
    int i = t >> 3, q = t & 7;
    if (i >= N) return;
    float di = dinv[i];
    float4 o = make_float4(0.f, 0.f, 0.f, 0.f);
#pragma unroll
    for (int k = 0; k < 5; k++) {
        float xv = x[i * 5 + k];
        float4 w = W1v[k * 8 + q];
        o.x = fmaf(xv, w.x, o.x); o.y = fmaf(xv, w.y, o.y);
        o.z = fmaf(xv, w.z, o.z); o.w = fmaf(xv, w.w, o.w);
    }
    o.x *= di; o.y *= di; o.z *= di; o.w *= di;
    S[(size_t)i * 8 + q] = o;
}

// ---- pull: val[i][q] = RELU?( dinv*(self + sum_nbr) + bias );
// FUSE_W2: Sout[i] = dinv[i] * (val_row @ W2) via LDS row exchange.
template<int RELU, int FUSE_W2>
__global__ void pull_kernel(const float4* __restrict__ Sin, const int* __restrict__ R,
                            const int* __restrict__ adj, const float* __restrict__ dinv,
                            const float* __restrict__ bias, const float4* __restrict__ W2v,
                            float4* __restrict__ Sout, int N, int E) {
    __shared__ float hsh[32][33];
    __shared__ float4 wsh[32][8];
    int t = blockIdx.x * blockDim.x + threadIdx.x;
    int i = t >> 3, q = t & 7;
    if (FUSE_W2) {
        wsh[threadIdx.x >> 3][threadIdx.x & 7] = W2v[threadIdx.x];
    }
    bool active = (i < N);
    float4 val = make_float4(0.f, 0.f, 0.f, 0.f);
    float di = 0.f;
    if (active) {
        float4 acc = Sin[(size_t)i * 8 + q];            // self-loop
        int s = __builtin_nontemporal_load(&R[i]);
        int e2 = (i == N - 1) ? E : __builtin_nontemporal_load(&R[i + 1]);
        for (int k = s; k < e2; k++) {
            int u = __builtin_nontemporal_load(&adj[k]);
            float4 v = Sin[(size_t)u * 8 + q];
            acc.x += v.x; acc.y += v.y; acc.z += v.z; acc.w += v.w;
        }
        di = dinv[i];
        float4 b = bias ? make_float4(bias[q*4], bias[q*4+1], bias[q*4+2], bias[q*4+3])
                        : make_float4(0.f, 0.f, 0.f, 0.f);
        val.x = fmaf(di, acc.x, b.x); val.y = fmaf(di, acc.y, b.y);
        val.z = fmaf(di, acc.z, b.z); val.w = fmaf(di, acc.w, b.w);
        if (RELU) {
            val.x = fmaxf(val.x, 0.f); val.y = fmaxf(val.y, 0.f);
            val.z = fmaxf(val.z, 0.f); val.w = fmaxf(val.w, 0.f);
        }
    }
    if constexpr (FUSE_W2) {
        int local = threadIdx.x >> 3;
        if (active) {
            hsh[local][q * 4 + 0] = val.x; hsh[local][q * 4 + 1] = val.y;
            hsh[local][q * 4 + 2] = val.z; hsh[local][q * 4 + 3] = val.w;
        }
        __syncthreads();
        if (active) {
            float4 o = make_float4(0.f, 0.f, 0.f, 0.f);
#pragma unroll
            for (int k = 0; k < H; k++) {
                float hk = hsh[local][k];
                float4 w = wsh[k][q];
                o.x = fmaf(hk, w.x, o.x); o.y = fmaf(hk, w.y, o.y);
                o.z = fmaf(hk, w.z, o.z); o.w = fmaf(hk, w.w, o.w);
            }
            o.x *= di; o.y *= di; o.z *= di; o.w *= di;
            Sout[(size_t)i * 8 + q] = o;
        }
    } else {
        if (active) Sout[(size_t)i * 8 + q] = val;
    }
}

// ---- pooling ----
__global__ void bounds_kernel(const int* __restrict__ batch, int* __restrict__ startg,
                              int* __restrict__ endg, int N) {
    int i = blockIdx.x * blockDim.x + threadIdx.x;
    if (i >= N) return;
    int g = batch[i];
    if (i == 0 || batch[i - 1] != g) startg[g] = i;
    if (i == N - 1 || batch[i + 1] != g) endg[g] = i + 1;
}

__global__ void pool_kernel(const float4* __restrict__ H2, const int* __restrict__ batch,
                            float* __restrict__ pooled, int N) {
    const int q = threadIdx.x & 7;
    const int r = threadIdx.x >> 3;
    const int ROWS = 32;
    long long base = (long long)blockIdx.x * POOL_CHUNK;
    long long end = base + POOL_CHUNK;
    if (end > N) end = N;
    float4 acc = make_float4(0.f, 0.f, 0.f, 0.f);
    int cur_g = -1;
    for (long long i = base + r; i < end; i += ROWS) {
        int g = batch[i];
        float4 v = H2[i * 8 + q];
        if (g != cur_g) {
            if (cur_g >= 0) {
                float* p = &pooled[(size_t)cur_g * H + q * 4];
                atomicAdd(p + 0, acc.x); atomicAdd(p + 1, acc.y);
                atomicAdd(p + 2, acc.z); atomicAdd(p + 3, acc.w);
            }
            acc = make_float4(0.f, 0.f, 0.f, 0.f);
            cur_g = g;
        }
        acc.x += v.x; acc.y += v.y; acc.z += v.z; acc.w += v.w;
    }
    if (cur_g >= 0) {
        float* p = &pooled[(size_t)cur_g * H + q * 4];
        atomicAdd(p + 0, acc.x); atomicAdd(p + 1, acc.y);
        atomicAdd(p + 2, acc.z); atomicAdd(p + 3, acc.w);
    }
}

// out[g] = (pooled[g]/cnt + b2) @ Wfc + bfc   (b2 commutes through mean)
__global__ void final_kernel(const float* __restrict__ pooled, const int* __restrict__ startg,
                             const int* __restrict__ endg, const float* __restrict__ b2,
                             const float* __restrict__ Wfc, const float* __restrict__ bfc,
                             float* __restrict__ out, int G) {
    int g = blockIdx.x * blockDim.x + threadIdx.x;
    if (g >= G) return;
    float cnt = (float)(endg[g] - startg[g]);
    float inv = 1.0f / fmaxf(cnt, 1.0f);
    float s0 = 0.f, s1 = 0.f;
#pragma unroll
    for (int j = 0; j < H; j++) {
        float p = fmaf(pooled[g * H + j], inv, b2[j]);
        s0 = fmaf(p, Wfc[j * 2 + 0], s0);
        s1 = fmaf(p, Wfc[j * 2 + 1], s1);
    }
    out[g * 2 + 0] = s0 + bfc[0];
    out[g * 2 + 1] = s1 + bfc[1];
}

extern "C" void kernel_launch(void* const* d_in, const int* in_sizes, int n_in,
                              void* d_out, int out_size, void* d_ws, size_t ws_size,
                              hipStream_t stream) {
    const float* x    = (const float*)d_in[0];
    const float* W1   = (const float*)d_in[1];
    const float* b1   = (const float*)d_in[2];
    const float* W2   = (const float*)d_in[3];
    const float* b2   = (const float*)d_in[4];
    const float* Wfc  = (const float*)d_in[5];
    const float* bfc  = (const float*)d_in[6];
    const int*   eidx = (const int*)d_in[7];
    const int*   batch= (const int*)d_in[8];
    float* out = (float*)d_out;

    const int N = in_sizes[0] / 5;
    const int E = in_sizes[7] / 2;
    const int G = out_size / 2;
    const int NB = (N + BNODES - 1) >> SHIFT;   // 7813 for N=500k (must be <= 8192)

    const int* src = eidx;
    const int* dst = eidx + E;

    char* ws = (char*)d_ws;
    size_t off = 0;
    auto alloc = [&](size_t bytes) { char* p = ws + off; off = (off + bytes + 255) & ~(size_t)255; return p; };
    int*      R      = (int*)alloc((size_t)N * 4);          // counts -> rowptr (in place)
    int*      adj    = (int*)alloc((size_t)E * 4);
    unsigned* packed = (unsigned*)alloc((size_t)E * 4);
    int*      bcnt   = (int*)alloc((size_t)NB * PAD * 4);
    int*      bcur   = (int*)alloc((size_t)NB * PAD * 4);
    int*      boff   = (int*)alloc((size_t)(NB + 1) * 4);
    int*      bsum   = (int*)alloc(4096);
    float*    dinv   = (float*)alloc((size_t)N * 4);
    float*    S1     = (float*)alloc((size_t)N * H * 4);
    float*    S2     = (float*)alloc((size_t)N * H * 4);
    float*    pooled = (float*)alloc((size_t)G * H * 4);    // pooled/startg/endg contiguous
    int*      startg = (int*)alloc((size_t)G * 4);
    int*      endg   = (int*)alloc((size_t)G * 4);
    (void)ws_size;

    const int T = 256;
    auto nb = [&](long long n) { return (int)((n + T - 1) / T); };
    const int nscan = (N + 1023) / 1024;   // 489 (must be <= 1024)

    hipMemsetAsync(bcnt, 0, (size_t)NB * PAD * 4, stream);
    hipMemsetAsync(pooled, 0, (size_t)G * H * 4 + (size_t)G * 4 * 2, stream);

    // CSR build via bucket radix partition
    bucket_hist_kernel<<<nb(E), T, 0, stream>>>(dst, bcnt, E);
    bucket_scan_kernel<<<1, 1024, 0, stream>>>(bcnt, boff, bcur, NB);
    partition_kernel<<<nb(E), T, 0, stream>>>(src, dst, bcur, packed, E);
    node_cnt_kernel<<<NB, T, 0, stream>>>(packed, boff, R, N);
    scan1_kernel<<<nscan, 256, 0, stream>>>(R, bsum, dinv, N);
    scan2_kernel<<<1, 1024, 0, stream>>>(bsum, nscan);
    scan3_kernel<<<nb(N), T, 0, stream>>>(R, bsum, N);
    bucket_scatter_kernel<<<NB, T, 0, stream>>>(packed, boff, R, adj, N);

    // layer 1 (+ fused W2 transform)
    lin1_kernel<<<nb((long long)N * 8), T, 0, stream>>>(x, (const float4*)W1, dinv, (float4*)S1, N);
    pull_kernel<1, 1><<<nb((long long)N * 8), T, 0, stream>>>(
        (const float4*)S1, R, adj, dinv, b1, (const float4*)W2, (float4*)S2, N, E);

    // layer 2
    pull_kernel<0, 0><<<nb((long long)N * 8), T, 0, stream>>>(
        (const float4*)S2, R, adj, dinv, nullptr, nullptr, (float4*)S1, N, E);

    // pool + fc
    bounds_kernel<<<nb(N), T, 0, stream>>>(batch, startg, endg, N);
    pool_kernel<<<(N + POOL_CHUNK - 1) / POOL_CHUNK, T, 0, stream>>>(
        (const float4*)S1, batch, pooled, N);
    final_kernel<<<nb(G), T, 0, stream>>>(pooled, startg, endg, b2, Wfc, bfc, out, G);
}